// Round 10
// baseline (445.486 us; speedup 1.0000x reference)
//
#include <hip/hip_runtime.h>
#include <cstdint>
#include <cstddef>

#define NREL 8

typedef __attribute__((ext_vector_type(8))) short bfrag8;   // 8 bf16 (4 VGPR)
typedef __attribute__((ext_vector_type(4))) float facc4;    // mfma accumulator

__device__ __forceinline__ ushort f2bf(float f) {           // fp32 -> bf16 RNE
  union { float f; uint u; } v; v.f = f;
  uint u = v.u + 0x7fffu + ((v.u >> 16) & 1u);
  return (ushort)(u >> 16);
}
__device__ __forceinline__ float bf2f(ushort u) {
  union { uint u; float f; } v; v.u = ((uint)u) << 16;
  return v.f;
}
__device__ __forceinline__ float readlane_f(float v, int l) {
  union { float f; int i; } u; u.f = v;
  u.i = __builtin_amdgcn_readlane(u.i, l);
  return u.f;
}

// ---------------------------------------------------------------------------
// all 4 weight transpose-converts in one kernel: out[r][n][k] = in[r][k][n]
// ---------------------------------------------------------------------------
__global__ __launch_bounds__(256) void cvt_all_kernel(const float* __restrict__ W1,
                                                      const float* __restrict__ r1,
                                                      const float* __restrict__ W2,
                                                      const float* __restrict__ r2,
                                                      ushort* __restrict__ W1t,
                                                      ushort* __restrict__ r1t,
                                                      ushort* __restrict__ W2t,
                                                      ushort* __restrict__ r2t) {
  int idx = blockIdx.x * 256 + threadIdx.x;
  const float* in; ushort* out; int K, N, rel;
  if (idx < 65536)        { in = W1; out = W1t; K = 128; N = 64;  rel = idx >> 13; idx &= 8191; }
  else if (idx < 73728)   { idx -= 65536; in = r1; out = r1t; K = 128; N = 64; rel = 0; }
  else if (idx < 139264)  { idx -= 73728; in = W2; out = W2t; K = 64; N = 128; rel = idx >> 13; idx &= 8191; }
  else if (idx < 147456)  { idx -= 139264; in = r2; out = r2t; K = 64; N = 128; rel = 0; }
  else return;
  int n = idx / K, k = idx - n * K;
  out[(size_t)rel * K * N + (size_t)n * K + k] =
      f2bf(in[(size_t)rel * K * N + (size_t)k * N + n]);
}

// ---------------------------------------------------------------------------
// FUSED: histogram (rel-major hist[rel*M+dst] + rank, 4 edges/thread)
//        || gemm_xt.  1:1 block interleave for latency hiding.
// ---------------------------------------------------------------------------
__global__ __launch_bounds__(256) void fused1_kernel(const float* __restrict__ x,
                                                     const ushort* __restrict__ W1t,
                                                     ushort* __restrict__ xt,
                                                     const int* __restrict__ dst,
                                                     const int* __restrict__ et,
                                                     uint* __restrict__ hist,
                                                     uint* __restrict__ rank,
                                                     int M, int E, int HB) {
  __shared__ __align__(16) ushort Axs[64][136];
  __shared__ __align__(16) ushort Bws[64][136];
  const int bid = blockIdx.x;
  const int hq = bid >> 1;
  if (((bid & 1) == 0) && hq < HB) {
    // ---------------- hist role: 4 edges/thread ----------------
    int base = (hq * 256 + threadIdx.x) * 4;
    if (base + 4 <= E) {
      int4 d = *(const int4*)&dst[base];
      int4 r = *(const int4*)&et[base];
      uint rk0 = atomicAdd(&hist[(size_t)r.x * M + d.x], 1u);
      uint rk1 = atomicAdd(&hist[(size_t)r.y * M + d.y], 1u);
      uint rk2 = atomicAdd(&hist[(size_t)r.z * M + d.z], 1u);
      uint rk3 = atomicAdd(&hist[(size_t)r.w * M + d.w], 1u);
      *(uint4*)&rank[base] = make_uint4(rk0, rk1, rk2, rk3);
    } else {
      for (int j = 0; base + j < E; ++j)
        rank[base + j] = atomicAdd(&hist[(size_t)et[base + j] * M + dst[base + j]], 1u);
    }
    return;
  }
  // ---------------- gemm_xt role ----------------
  const int gidx = (hq < HB) ? (bid - hq - 1) : (bid - HB);
  const int tid = threadIdx.x;
  const int w = tid >> 6, l = tid & 63;
  const int rows0 = gidx * 64;
#pragma unroll
  for (int i = 0; i < 8; ++i) {
    int g = tid + 256 * i;
    int row = g >> 5, c4 = (g & 31) * 4;
    int rr = rows0 + row; if (rr >= M) rr = M - 1;
    float4 v = *(const float4*)&x[(size_t)rr * 128 + c4];
    *(ushort4*)&Axs[row][c4] = make_ushort4(f2bf(v.x), f2bf(v.y), f2bf(v.z), f2bf(v.w));
  }
  __syncthreads();
  const int mrow = w * 16 + (l & 15);
  const int koff = (l >> 4) * 8;
  bfrag8 xf[4];
#pragma unroll
  for (int kc = 0; kc < 4; ++kc)
    xf[kc] = *(const bfrag8*)&Axs[mrow][kc * 32 + koff];
  const int m = rows0 + mrow;
  for (int r = 0; r < NREL; ++r) {
    __syncthreads();
#pragma unroll
    for (int i = 0; i < 8; ++i) {
      int g = tid + 256 * i;
      int row = g >> 5, c4 = (g & 31) * 4;
      *(ushort4*)&Bws[row][c4] = *(const ushort4*)&W1t[((size_t)r * 64 + row) * 128 + c4];
    }
    __syncthreads();
#pragma unroll
    for (int ct = 0; ct < 4; ++ct) {
      facc4 acc = {0.f, 0.f, 0.f, 0.f};
#pragma unroll
      for (int kc = 0; kc < 4; ++kc) {
        bfrag8 af = *(const bfrag8*)&Bws[ct * 16 + (l & 15)][kc * 32 + koff];
        acc = __builtin_amdgcn_mfma_f32_16x16x32_bf16(af, xf[kc], acc, 0, 0, 0);
      }
      if (m < M) {
        int n0 = ct * 16 + (l >> 4) * 4;
        *(ushort4*)&xt[(size_t)m * 512 + r * 64 + n0] =
            make_ushort4(f2bf(acc[0]), f2bf(acc[1]), f2bf(acc[2]), f2bf(acc[3]));
      }
    }
  }
}

// ---------------------------------------------------------------------------
// scan stage 1: per-block sums over dst-major segment order
// ---------------------------------------------------------------------------
__global__ __launch_bounds__(256) void scan1_kernel(const uint* __restrict__ hist,
                                                    uint* __restrict__ bsum, int M) {
  __shared__ uint r[256];
  int b = blockIdx.x, t = threadIdx.x;
  int d = b * 256 + t;
  uint s = 0;
  if (d < M) {
#pragma unroll
    for (int i = 0; i < 8; ++i) s += hist[(size_t)i * M + d];
  }
  r[t] = s; __syncthreads();
  for (int dd = 128; dd > 0; dd >>= 1) { if (t < dd) r[t] += r[t + dd]; __syncthreads(); }
  if (t == 0) bsum[b] = r[0];
}

__global__ __launch_bounds__(512) void scan2_kernel(uint* __restrict__ bsum, int nb) {
  __shared__ uint s[512];
  int t = threadIdx.x;
  uint v = (t < nb) ? bsum[t] : 0u;
  s[t] = v;
  __syncthreads();
  for (int d = 1; d < 512; d <<= 1) {
    uint add = (t >= d) ? s[t - d] : 0u;
    __syncthreads();
    s[t] += add;
    __syncthreads();
  }
  if (t < nb) bsum[t] = s[t] - v;   // exclusive
}

// ---------------------------------------------------------------------------
// scan stage 3: off[d*8+r], idg[d*8+r] (dst-major) from rel-major hist
// ---------------------------------------------------------------------------
__global__ __launch_bounds__(256) void scan3_kernel(const uint* __restrict__ hist,
                                                    const uint* __restrict__ bsum,
                                                    uint* __restrict__ off,
                                                    float* __restrict__ idg,
                                                    int M, int E) {
  __shared__ uint ts[256];
  int b = blockIdx.x, t = threadIdx.x;
  int d = b * 256 + t;
  uint h[8]; uint sum = 0;
#pragma unroll
  for (int i = 0; i < 8; ++i) { h[i] = (d < M) ? hist[(size_t)i * M + d] : 0u; sum += h[i]; }
  ts[t] = sum;
  __syncthreads();
  uint own = sum;
  for (int dd = 1; dd < 256; dd <<= 1) {
    uint add = (t >= dd) ? ts[t - dd] : 0u;
    __syncthreads();
    ts[t] += add;
    __syncthreads();
  }
  uint run = bsum[b] + (ts[t] - own);
  if (d < M) {
#pragma unroll
    for (int i = 0; i < 8; ++i) {
      int k = d * 8 + i;
      off[k] = run;
      idg[k] = 1.0f / fmaxf((float)h[i], 1.0f);
      run += h[i];
    }
    if (d == M - 1) off[M * 8] = (uint)E;
  }
}

// ---------------------------------------------------------------------------
// placement (atomic-free): sp[off[s] + rank[e]] = (src<<7) | (rel<<4)
// ---------------------------------------------------------------------------
__global__ __launch_bounds__(256) void place_kernel(const int* __restrict__ src,
                                                    const int* __restrict__ dst,
                                                    const int* __restrict__ et,
                                                    const uint* __restrict__ off,
                                                    const uint* __restrict__ rank,
                                                    uint* __restrict__ sp, int E) {
  int base = (blockIdx.x * 256 + threadIdx.x) * 8;
  if (base + 8 <= E) {
    int4 d0 = *(const int4*)&dst[base], d1 = *(const int4*)&dst[base + 4];
    int4 r0 = *(const int4*)&et[base],  r1 = *(const int4*)&et[base + 4];
    int4 s0 = *(const int4*)&src[base], s1 = *(const int4*)&src[base + 4];
    uint4 k0 = *(const uint4*)&rank[base], k1 = *(const uint4*)&rank[base + 4];
    int dd[8] = {d0.x, d0.y, d0.z, d0.w, d1.x, d1.y, d1.z, d1.w};
    int rr[8] = {r0.x, r0.y, r0.z, r0.w, r1.x, r1.y, r1.z, r1.w};
    int ss[8] = {s0.x, s0.y, s0.z, s0.w, s1.x, s1.y, s1.z, s1.w};
    uint kk[8] = {k0.x, k0.y, k0.z, k0.w, k1.x, k1.y, k1.z, k1.w};
    uint oo[8];
#pragma unroll
    for (int j = 0; j < 8; ++j) oo[j] = off[(size_t)dd[j] * NREL + rr[j]];
#pragma unroll
    for (int j = 0; j < 8; ++j)
      sp[oo[j] + kk[j]] = ((uint)ss[j] << 7) | ((uint)rr[j] << 4);
  } else {
    for (int j = 0; base + j < E; ++j) {
      int e = base + j;
      int r = et[e];
      sp[off[(size_t)dst[e] * NREL + r] + rank[e]] = ((uint)src[e] << 7) | ((uint)r << 4);
    }
  }
}

// ---------------------------------------------------------------------------
// fusedA: agg1 (phase A, LDS) + reduce_h (phase B, MFMA). 64 dsts/block.
// ---------------------------------------------------------------------------
__global__ __launch_bounds__(256) void fusedA_kernel(const uint* __restrict__ off,
                                                     const uint* __restrict__ sp,
                                                     const float* __restrict__ idg,
                                                     const ushort* __restrict__ xt,
                                                     const float* __restrict__ x,
                                                     const ushort* __restrict__ r1t,
                                                     const float* __restrict__ b1,
                                                     ushort* __restrict__ hb, int M) {
  __shared__ __align__(16) float aggs[64][68];
  __shared__ __align__(16) ushort Axs[64][136];
  __shared__ __align__(16) ushort Bws[64][136];
  const int tid = threadIdx.x;
  const int w = tid >> 6, l = tid & 63;
  const int m0 = blockIdx.x * 64;
  // stage x tile + r1t (before phase A so LDS traffic overlaps gathers)
#pragma unroll
  for (int i = 0; i < 8; ++i) {
    int g = tid + 256 * i;
    int row = g >> 5, c4 = (g & 31) * 4;
    int rr = m0 + row; if (rr >= M) rr = M - 1;
    float4 v = *(const float4*)&x[(size_t)rr * 128 + c4];
    *(ushort4*)&Axs[row][c4] = make_ushort4(f2bf(v.x), f2bf(v.y), f2bf(v.z), f2bf(v.w));
    *(ushort4*)&Bws[row][c4] = *(const ushort4*)&r1t[(size_t)row * 128 + c4];
  }
  // ---- phase A: each wave aggregates 16 dsts ----
  const uint lane2 = (uint)l * 2u;
  const char* xb = (const char*)xt;
  for (int t = 0; t < 16; ++t) {
    int wid = m0 + w * 16 + t;
    if (wid >= M) break;
    uint e0 = (uint)__builtin_amdgcn_readfirstlane((int)off[(size_t)wid * 8]);
    uint e1 = (uint)__builtin_amdgcn_readfirstlane((int)off[(size_t)wid * 8 + 8]);
    float idgl = (l < 8) ? idg[(size_t)wid * 8 + l] : 0.f;
    float acct = 0.f, accs = 0.f;
    uint cur = 0;
    for (uint b0 = e0; b0 < e1; b0 += 64) {
      uint vsp = sp[b0 + l];                       // sp over-allocated by 64
      uint vpr = __shfl(vsp, (l - 1) & 63);
      unsigned long long bmv = __ballot(((vsp ^ vpr) & 0x70u) != 0u);
      uint blo = (uint)__builtin_amdgcn_readfirstlane((int)(uint)bmv);
      uint bhi = (uint)__builtin_amdgcn_readfirstlane((int)(uint)(bmv >> 32));
      uint f0  = (uint)__builtin_amdgcn_readlane((int)vsp, 0);
      if ((b0 == e0) || (((f0 ^ cur) & 0x70u) != 0u)) blo |= 1u; else blo &= ~1u;
      unsigned long long sbm = (((unsigned long long)bhi) << 32) | blo;
      int n = min(64, (int)(e1 - b0));
      int i = 0;
      for (; i + 8 <= n; i += 8) {
        uint p[8]; float v[8];
#pragma unroll
        for (int j = 0; j < 8; ++j)
          p[j] = (uint)__builtin_amdgcn_readlane((int)vsp, i + j);
#pragma unroll
        for (int j = 0; j < 8; ++j)
          v[j] = bf2f(*(const ushort*)(xb + (size_t)((p[j] << 3) + lane2)));
#pragma unroll
        for (int j = 0; j < 8; ++j) {
          if ((sbm >> j) & 1ull) {
            acct += accs * readlane_f(idgl, (int)((cur >> 4) & 7u));
            accs = 0.f; cur = p[j];
          }
          accs += v[j];
        }
        sbm >>= 8;
      }
      for (; i < n; ++i) {
        uint pp = (uint)__builtin_amdgcn_readlane((int)vsp, i);
        float vv = bf2f(*(const ushort*)(xb + (size_t)((pp << 3) + lane2)));
        if (sbm & 1ull) {
          acct += accs * readlane_f(idgl, (int)((cur >> 4) & 7u));
          accs = 0.f; cur = pp;
        }
        sbm >>= 1;
        accs += vv;
      }
    }
    acct += accs * readlane_f(idgl, (int)((cur >> 4) & 7u));
    aggs[w * 16 + t][l] = acct;
  }
  __syncthreads();
  // ---- phase B: reduce_h MFMA ----
  const int mrow = w * 16 + (l & 15);
  const int koff = (l >> 4) * 8;
  const int m = m0 + mrow;
  bfrag8 xf[4];
#pragma unroll
  for (int kc = 0; kc < 4; ++kc)
    xf[kc] = *(const bfrag8*)&Axs[mrow][kc * 32 + koff];
  facc4 acc[4] = {};
#pragma unroll
  for (int ct = 0; ct < 4; ++ct)
#pragma unroll
    for (int kc = 0; kc < 4; ++kc) {
      bfrag8 af = *(const bfrag8*)&Bws[ct * 16 + (l & 15)][kc * 32 + koff];
      acc[ct] = __builtin_amdgcn_mfma_f32_16x16x32_bf16(af, xf[kc], acc[ct], 0, 0, 0);
    }
#pragma unroll
  for (int ct = 0; ct < 4; ++ct) {
    int n0 = ct * 16 + (l >> 4) * 4;
    float4 s4 = *(const float4*)&aggs[mrow][n0];
    float4 bb = *(const float4*)&b1[n0];
    float h0 = fmaxf(acc[ct][0] + s4.x + bb.x, 0.f);
    float h1 = fmaxf(acc[ct][1] + s4.y + bb.y, 0.f);
    float h2 = fmaxf(acc[ct][2] + s4.z + bb.z, 0.f);
    float h3 = fmaxf(acc[ct][3] + s4.w + bb.w, 0.f);
    if (m < M)
      *(ushort4*)&hb[(size_t)m * 64 + n0] =
          make_ushort4(f2bf(h0), f2bf(h1), f2bf(h2), f2bf(h3));
  }
}

// ---------------------------------------------------------------------------
// fusedB: agg2 (phase A -> LDS Ys) + gemm_out (phase B). 32 dsts/block.
// phase B: wave (w>>1) = row group of 16, (w&1) = col group of 64.
// ---------------------------------------------------------------------------
__global__ __launch_bounds__(256) void fusedB_kernel(const uint* __restrict__ off,
                                                     const uint* __restrict__ sp,
                                                     const float* __restrict__ idg,
                                                     const ushort* __restrict__ hb,
                                                     const ushort* __restrict__ W2t,
                                                     const ushort* __restrict__ r2t,
                                                     const float* __restrict__ b2,
                                                     float* __restrict__ out, int M) {
  __shared__ __align__(16) ushort Ys[32][520];    // pad: 1040B rows, 16B aligned
  __shared__ __align__(16) ushort Bws[128][72];
  const int tid = threadIdx.x;
  const int w = tid >> 6, l = tid & 63;
  const int m0 = blockIdx.x * 32;
  const uint lane2 = (uint)l * 2u;
  const char* hbb = (const char*)hb;
  // ---- phase A: each wave aggregates 8 dsts into Ys ----
  for (int t = 0; t < 8; ++t) {
    int wid = m0 + w * 8 + t;
    int ld = w * 8 + t;
    if (wid >= M) break;
    uint e0 = (uint)__builtin_amdgcn_readfirstlane((int)off[(size_t)wid * 8]);
    uint e1 = (uint)__builtin_amdgcn_readfirstlane((int)off[(size_t)wid * 8 + 8]);
    float idgl = (l < 8) ? idg[(size_t)wid * 8 + l] : 0.f;
    float accs = 0.f;
    uint cur = 0;
    bool live = false;
    uint written = 0;
    for (uint b0 = e0; b0 < e1; b0 += 64) {
      uint vsp = sp[b0 + l];
      uint vpr = __shfl(vsp, (l - 1) & 63);
      unsigned long long bmv = __ballot(((vsp ^ vpr) & 0x70u) != 0u);
      uint blo = (uint)__builtin_amdgcn_readfirstlane((int)(uint)bmv);
      uint bhi = (uint)__builtin_amdgcn_readfirstlane((int)(uint)(bmv >> 32));
      uint f0  = (uint)__builtin_amdgcn_readlane((int)vsp, 0);
      if ((b0 == e0) || (((f0 ^ cur) & 0x70u) != 0u)) blo |= 1u; else blo &= ~1u;
      unsigned long long sbm = (((unsigned long long)bhi) << 32) | blo;
      int n = min(64, (int)(e1 - b0));
      int i = 0;
      for (; i + 8 <= n; i += 8) {
        uint p[8]; float v[8];
#pragma unroll
        for (int j = 0; j < 8; ++j)
          p[j] = (uint)__builtin_amdgcn_readlane((int)vsp, i + j);
#pragma unroll
        for (int j = 0; j < 8; ++j)
          v[j] = bf2f(*(const ushort*)(hbb + (size_t)((p[j] & ~127u) + lane2)));
#pragma unroll
        for (int j = 0; j < 8; ++j) {
          if ((sbm >> j) & 1ull) {
            if (live) {
              int r = (int)((cur >> 4) & 7u);
              Ys[ld][r * 64 + l] = f2bf(accs * readlane_f(idgl, r));
              written |= 1u << r;
            }
            accs = 0.f; cur = p[j]; live = true;
          }
          accs += v[j];
        }
        sbm >>= 8;
      }
      for (; i < n; ++i) {
        uint pp = (uint)__builtin_amdgcn_readlane((int)vsp, i);
        float vv = bf2f(*(const ushort*)(hbb + (size_t)((pp & ~127u) + lane2)));
        if (sbm & 1ull) {
          if (live) {
            int r = (int)((cur >> 4) & 7u);
            Ys[ld][r * 64 + l] = f2bf(accs * readlane_f(idgl, r));
            written |= 1u << r;
          }
          accs = 0.f; cur = pp; live = true;
        }
        sbm >>= 1;
        accs += vv;
      }
    }
    if (live) {
      int r = (int)((cur >> 4) & 7u);
      Ys[ld][r * 64 + l] = f2bf(accs * readlane_f(idgl, r));
      written |= 1u << r;
    }
#pragma unroll
    for (int r = 0; r < 8; ++r)
      if (!((written >> r) & 1u))
        Ys[ld][r * 64 + l] = 0;
  }
  // ---- phase B: GEMM.  stage r2t, barrier covers phase A + staging ----
#pragma unroll
  for (int i = 0; i < 8; ++i) {
    int g = tid + 256 * i;
    int row = g >> 4, c4 = (g & 15) * 4;
    *(ushort4*)&Bws[row][c4] = *(const ushort4*)&r2t[(size_t)row * 64 + c4];
  }
  __syncthreads();
  const int rg = w >> 1, cg = w & 1;
  const int mrow = rg * 16 + (l & 15);
  const int koff = (l >> 4) * 8;
  const int m = m0 + mrow;
  const int mc = (m < M) ? m : (M - 1);
  facc4 oacc[4] = {};
  {
    bfrag8 h0 = *(const bfrag8*)&hb[(size_t)mc * 64 + koff];
    bfrag8 h1 = *(const bfrag8*)&hb[(size_t)mc * 64 + 32 + koff];
#pragma unroll
    for (int ct = 0; ct < 4; ++ct) {
      bfrag8 a0 = *(const bfrag8*)&Bws[cg * 64 + ct * 16 + (l & 15)][koff];
      bfrag8 a1 = *(const bfrag8*)&Bws[cg * 64 + ct * 16 + (l & 15)][32 + koff];
      oacc[ct] = __builtin_amdgcn_mfma_f32_16x16x32_bf16(a0, h0, oacc[ct], 0, 0, 0);
      oacc[ct] = __builtin_amdgcn_mfma_f32_16x16x32_bf16(a1, h1, oacc[ct], 0, 0, 0);
    }
  }
  for (int r = 0; r < NREL; ++r) {
    __syncthreads();
#pragma unroll
    for (int i = 0; i < 8; ++i) {
      int g = tid + 256 * i;
      int row = g >> 4, c4 = (g & 15) * 4;
      *(ushort4*)&Bws[row][c4] = *(const ushort4*)&W2t[((size_t)r * 128 + row) * 64 + c4];
    }
    __syncthreads();
    bfrag8 y0 = *(const bfrag8*)&Ys[mrow][r * 64 + koff];
    bfrag8 y1f = *(const bfrag8*)&Ys[mrow][r * 64 + 32 + koff];
#pragma unroll
    for (int ct = 0; ct < 4; ++ct) {
      bfrag8 a0 = *(const bfrag8*)&Bws[cg * 64 + ct * 16 + (l & 15)][koff];
      bfrag8 a1 = *(const bfrag8*)&Bws[cg * 64 + ct * 16 + (l & 15)][32 + koff];
      oacc[ct] = __builtin_amdgcn_mfma_f32_16x16x32_bf16(a0, y0, oacc[ct], 0, 0, 0);
      oacc[ct] = __builtin_amdgcn_mfma_f32_16x16x32_bf16(a1, y1f, oacc[ct], 0, 0, 0);
    }
  }
  if (m < M) {
#pragma unroll
    for (int ct = 0; ct < 4; ++ct) {
      int n0 = cg * 64 + ct * 16 + (l >> 4) * 4;
      float4 bb = *(const float4*)&b2[n0];
      float4 o = make_float4(oacc[ct][0] + bb.x, oacc[ct][1] + bb.y,
                             oacc[ct][2] + bb.z, oacc[ct][3] + bb.w);
      *(float4*)&out[(size_t)m * 128 + n0] = o;
    }
  }
}

// ---------------------------------------------------------------------------
extern "C" void kernel_launch(void* const* d_in, const int* in_sizes, int n_in,
                              void* d_out, int out_size, void* d_ws, size_t ws_size,
                              hipStream_t stream) {
  const float* x     = (const float*)d_in[0];
  const int*   ei    = (const int*)d_in[1];
  const int*   et    = (const int*)d_in[2];
  const float* W1    = (const float*)d_in[3];
  const float* root1 = (const float*)d_in[4];
  const float* b1    = (const float*)d_in[5];
  const float* W2    = (const float*)d_in[6];
  const float* root2 = (const float*)d_in[7];
  const float* b2    = (const float*)d_in[8];
  float* out = (float*)d_out;

  const int M = in_sizes[0] / 128;   // 100000
  const int E = in_sizes[2];         // 1600000
  const int NS = M * NREL;           // segments
  const int* srcp = ei;
  const int* dstp = ei + E;

  auto align = [](char*& p, size_t n) { char* q = p; p += (n + 255) & ~(size_t)255; return q; };
  char* p = (char*)d_ws;
  ushort* xt   = (ushort*)align(p, (size_t)M * 512 * 2);
  ushort* hb   = (ushort*)align(p, (size_t)M * 64 * 2);
  uint*   hist = (uint*)  align(p, (size_t)NS * 4);
  uint*   rank = (uint*)  align(p, (size_t)E * 4);
  uint*   off  = (uint*)  align(p, (size_t)(NS + 1) * 4);
  float*  idg  = (float*) align(p, (size_t)NS * 4);
  uint*   sp   = (uint*)  align(p, (size_t)(E + 64) * 4);  // +64 over-read slack
  uint*   bsum = (uint*)  align(p, 4096);
  ushort* W1t  = (ushort*)align(p, (size_t)NREL * 64 * 128 * 2);
  ushort* r1t  = (ushort*)align(p, (size_t)64 * 128 * 2);
  ushort* W2t  = (ushort*)align(p, (size_t)NREL * 128 * 64 * 2);
  ushort* r2t  = (ushort*)align(p, (size_t)128 * 64 * 2);

  cvt_all_kernel<<<(147456 + 255) / 256, 256, 0, stream>>>(W1, root1, W2, root2,
                                                           W1t, r1t, W2t, r2t);
  hipMemsetAsync(hist, 0, (size_t)NS * 4, stream);

  // ---- fused: hist(4/thread) || gemm_xt, 1:1 interleave ----
  const int E4B  = (int)(((long long)E + 4LL * 256 - 1) / (4LL * 256));
  const int MB64 = (M + 63) / 64;
  fused1_kernel<<<E4B + MB64, 256, 0, stream>>>(x, W1t, xt, dstp, et,
                                                hist, rank, M, E, E4B);

  // ---- scan -> place ----
  const int NB = (M + 255) / 256;
  scan1_kernel<<<NB, 256, 0, stream>>>(hist, bsum, M);
  scan2_kernel<<<1, 512, 0, stream>>>(bsum, NB);
  scan3_kernel<<<NB, 256, 0, stream>>>(hist, bsum, off, idg, M, E);
  const int E8B = (int)(((long long)E + 8LL * 256 - 1) / (8LL * 256));
  place_kernel<<<E8B, 256, 0, stream>>>(srcp, dstp, et, off, rank, sp, E);

  // ---- layer 1 fused: gather-aggregate + root GEMM + relu ----
  fusedA_kernel<<<MB64, 256, 0, stream>>>(off, sp, idg, xt, x, r1t, b1, hb, M);

  // ---- layer 2 fused: gather-aggregate (LDS) + GEMM + bias ----
  const int MB32 = (M + 31) / 32;
  fusedB_kernel<<<MB32, 256, 0, stream>>>(off, sp, idg, hb, W2t, r2t, b2, out, M);
}

// Round 11
// 320.945 us; speedup vs baseline: 1.3880x; 1.3880x over previous
//
#include <hip/hip_runtime.h>
#include <cstdint>
#include <cstddef>

#define NREL 8

typedef __attribute__((ext_vector_type(8))) short bfrag8;   // 8 bf16 (4 VGPR)
typedef __attribute__((ext_vector_type(4))) float facc4;    // mfma accumulator

__device__ __forceinline__ ushort f2bf(float f) {           // fp32 -> bf16 RNE
  union { float f; uint u; } v; v.f = f;
  uint u = v.u + 0x7fffu + ((v.u >> 16) & 1u);
  return (ushort)(u >> 16);
}
__device__ __forceinline__ float bf2f(ushort u) {
  union { uint u; float f; } v; v.u = ((uint)u) << 16;
  return v.f;
}
__device__ __forceinline__ float readlane_f(float v, int l) {
  union { float f; int i; } u; u.f = v;
  u.i = __builtin_amdgcn_readlane(u.i, l);
  return u.f;
}

// ---------------------------------------------------------------------------
// all 4 weight transpose-converts in one kernel: out[r][n][k] = in[r][k][n]
// ---------------------------------------------------------------------------
__global__ __launch_bounds__(256) void cvt_all_kernel(const float* __restrict__ W1,
                                                      const float* __restrict__ r1,
                                                      const float* __restrict__ W2,
                                                      const float* __restrict__ r2,
                                                      ushort* __restrict__ W1t,
                                                      ushort* __restrict__ r1t,
                                                      ushort* __restrict__ W2t,
                                                      ushort* __restrict__ r2t) {
  int idx = blockIdx.x * 256 + threadIdx.x;
  const float* in; ushort* out; int K, N, rel;
  if (idx < 65536)        { in = W1; out = W1t; K = 128; N = 64;  rel = idx >> 13; idx &= 8191; }
  else if (idx < 73728)   { idx -= 65536; in = r1; out = r1t; K = 128; N = 64; rel = 0; }
  else if (idx < 139264)  { idx -= 73728; in = W2; out = W2t; K = 64; N = 128; rel = idx >> 13; idx &= 8191; }
  else if (idx < 147456)  { idx -= 139264; in = r2; out = r2t; K = 64; N = 128; rel = 0; }
  else return;
  int n = idx / K, k = idx - n * K;
  out[(size_t)rel * K * N + (size_t)n * K + k] =
      f2bf(in[(size_t)rel * K * N + (size_t)k * N + n]);
}

// ---------------------------------------------------------------------------
// FUSED: histogram (rel-major hist[rel*M+dst] + rank, 4 edges/thread)
//        || gemm_xt.  1:1 block interleave for latency hiding.
// (hist TLP doubled vs 8/thread: atomic-with-return latency needs waves)
// ---------------------------------------------------------------------------
__global__ __launch_bounds__(256) void fused1_kernel(const float* __restrict__ x,
                                                     const ushort* __restrict__ W1t,
                                                     ushort* __restrict__ xt,
                                                     const int* __restrict__ dst,
                                                     const int* __restrict__ et,
                                                     uint* __restrict__ hist,
                                                     uint* __restrict__ rank,
                                                     int M, int E, int HB) {
  __shared__ __align__(16) ushort Axs[64][136];
  __shared__ __align__(16) ushort Bws[64][136];
  const int bid = blockIdx.x;
  const int hq = bid >> 1;
  if (((bid & 1) == 0) && hq < HB) {
    // ---------------- hist role: 4 edges/thread ----------------
    int base = (hq * 256 + threadIdx.x) * 4;
    if (base + 4 <= E) {
      int4 d = *(const int4*)&dst[base];
      int4 r = *(const int4*)&et[base];
      uint rk0 = atomicAdd(&hist[(size_t)r.x * M + d.x], 1u);
      uint rk1 = atomicAdd(&hist[(size_t)r.y * M + d.y], 1u);
      uint rk2 = atomicAdd(&hist[(size_t)r.z * M + d.z], 1u);
      uint rk3 = atomicAdd(&hist[(size_t)r.w * M + d.w], 1u);
      *(uint4*)&rank[base] = make_uint4(rk0, rk1, rk2, rk3);
    } else {
      for (int j = 0; base + j < E; ++j)
        rank[base + j] = atomicAdd(&hist[(size_t)et[base + j] * M + dst[base + j]], 1u);
    }
    return;
  }
  // ---------------- gemm_xt role ----------------
  const int gidx = (hq < HB) ? (bid - hq - 1) : (bid - HB);
  const int tid = threadIdx.x;
  const int w = tid >> 6, l = tid & 63;
  const int rows0 = gidx * 64;
#pragma unroll
  for (int i = 0; i < 8; ++i) {
    int g = tid + 256 * i;
    int row = g >> 5, c4 = (g & 31) * 4;
    int rr = rows0 + row; if (rr >= M) rr = M - 1;
    float4 v = *(const float4*)&x[(size_t)rr * 128 + c4];
    *(ushort4*)&Axs[row][c4] = make_ushort4(f2bf(v.x), f2bf(v.y), f2bf(v.z), f2bf(v.w));
  }
  __syncthreads();
  const int mrow = w * 16 + (l & 15);
  const int koff = (l >> 4) * 8;
  bfrag8 xf[4];
#pragma unroll
  for (int kc = 0; kc < 4; ++kc)
    xf[kc] = *(const bfrag8*)&Axs[mrow][kc * 32 + koff];
  const int m = rows0 + mrow;
  for (int r = 0; r < NREL; ++r) {
    __syncthreads();
#pragma unroll
    for (int i = 0; i < 8; ++i) {
      int g = tid + 256 * i;
      int row = g >> 5, c4 = (g & 31) * 4;
      *(ushort4*)&Bws[row][c4] = *(const ushort4*)&W1t[((size_t)r * 64 + row) * 128 + c4];
    }
    __syncthreads();
#pragma unroll
    for (int ct = 0; ct < 4; ++ct) {
      facc4 acc = {0.f, 0.f, 0.f, 0.f};
#pragma unroll
      for (int kc = 0; kc < 4; ++kc) {
        bfrag8 af = *(const bfrag8*)&Bws[ct * 16 + (l & 15)][kc * 32 + koff];
        acc = __builtin_amdgcn_mfma_f32_16x16x32_bf16(af, xf[kc], acc, 0, 0, 0);
      }
      if (m < M) {
        int n0 = ct * 16 + (l >> 4) * 4;
        *(ushort4*)&xt[(size_t)m * 512 + r * 64 + n0] =
            make_ushort4(f2bf(acc[0]), f2bf(acc[1]), f2bf(acc[2]), f2bf(acc[3]));
      }
    }
  }
}

// ---------------------------------------------------------------------------
// scan stage 1: per-block sums over dst-major segment order
// ---------------------------------------------------------------------------
__global__ __launch_bounds__(256) void scan1_kernel(const uint* __restrict__ hist,
                                                    uint* __restrict__ bsum, int M) {
  __shared__ uint r[256];
  int b = blockIdx.x, t = threadIdx.x;
  int d = b * 256 + t;
  uint s = 0;
  if (d < M) {
#pragma unroll
    for (int i = 0; i < 8; ++i) s += hist[(size_t)i * M + d];
  }
  r[t] = s; __syncthreads();
  for (int dd = 128; dd > 0; dd >>= 1) { if (t < dd) r[t] += r[t + dd]; __syncthreads(); }
  if (t == 0) bsum[b] = r[0];
}

__global__ __launch_bounds__(512) void scan2_kernel(uint* __restrict__ bsum, int nb) {
  __shared__ uint s[512];
  int t = threadIdx.x;
  uint v = (t < nb) ? bsum[t] : 0u;
  s[t] = v;
  __syncthreads();
  for (int d = 1; d < 512; d <<= 1) {
    uint add = (t >= d) ? s[t - d] : 0u;
    __syncthreads();
    s[t] += add;
    __syncthreads();
  }
  if (t < nb) bsum[t] = s[t] - v;   // exclusive
}

// ---------------------------------------------------------------------------
// scan stage 3: off[d*8+r], idg[d*8+r] (dst-major) from rel-major hist
// ---------------------------------------------------------------------------
__global__ __launch_bounds__(256) void scan3_kernel(const uint* __restrict__ hist,
                                                    const uint* __restrict__ bsum,
                                                    uint* __restrict__ off,
                                                    float* __restrict__ idg,
                                                    int M, int E) {
  __shared__ uint ts[256];
  int b = blockIdx.x, t = threadIdx.x;
  int d = b * 256 + t;
  uint h[8]; uint sum = 0;
#pragma unroll
  for (int i = 0; i < 8; ++i) { h[i] = (d < M) ? hist[(size_t)i * M + d] : 0u; sum += h[i]; }
  ts[t] = sum;
  __syncthreads();
  uint own = sum;
  for (int dd = 1; dd < 256; dd <<= 1) {
    uint add = (t >= dd) ? ts[t - dd] : 0u;
    __syncthreads();
    ts[t] += add;
    __syncthreads();
  }
  uint run = bsum[b] + (ts[t] - own);
  if (d < M) {
#pragma unroll
    for (int i = 0; i < 8; ++i) {
      int k = d * 8 + i;
      off[k] = run;
      idg[k] = 1.0f / fmaxf((float)h[i], 1.0f);
      run += h[i];
    }
    if (d == M - 1) off[M * 8] = (uint)E;
  }
}

// ---------------------------------------------------------------------------
// placement (atomic-free): sp[off[s] + rank[e]] = (src<<7) | (rel<<4)
// ---------------------------------------------------------------------------
__global__ __launch_bounds__(256) void place_kernel(const int* __restrict__ src,
                                                    const int* __restrict__ dst,
                                                    const int* __restrict__ et,
                                                    const uint* __restrict__ off,
                                                    const uint* __restrict__ rank,
                                                    uint* __restrict__ sp, int E) {
  int base = (blockIdx.x * 256 + threadIdx.x) * 8;
  if (base + 8 <= E) {
    int4 d0 = *(const int4*)&dst[base], d1 = *(const int4*)&dst[base + 4];
    int4 r0 = *(const int4*)&et[base],  r1 = *(const int4*)&et[base + 4];
    int4 s0 = *(const int4*)&src[base], s1 = *(const int4*)&src[base + 4];
    uint4 k0 = *(const uint4*)&rank[base], k1 = *(const uint4*)&rank[base + 4];
    int dd[8] = {d0.x, d0.y, d0.z, d0.w, d1.x, d1.y, d1.z, d1.w};
    int rr[8] = {r0.x, r0.y, r0.z, r0.w, r1.x, r1.y, r1.z, r1.w};
    int ss[8] = {s0.x, s0.y, s0.z, s0.w, s1.x, s1.y, s1.z, s1.w};
    uint kk[8] = {k0.x, k0.y, k0.z, k0.w, k1.x, k1.y, k1.z, k1.w};
    uint oo[8];
#pragma unroll
    for (int j = 0; j < 8; ++j) oo[j] = off[(size_t)dd[j] * NREL + rr[j]];
#pragma unroll
    for (int j = 0; j < 8; ++j)
      sp[oo[j] + kk[j]] = ((uint)ss[j] << 7) | ((uint)rr[j] << 4);
  } else {
    for (int j = 0; base + j < E; ++j) {
      int e = base + j;
      int r = et[e];
      sp[off[(size_t)dst[e] * NREL + r] + rank[e]] = ((uint)src[e] << 7) | ((uint)r << 4);
    }
  }
}

// ---------------------------------------------------------------------------
// agg1[d][lane] = sum_r idg[d,r] * sum_{e in seg(d,r)} xt[src_e][r][lane]
// one wave per dst (max TLP — fusion with GEMM config regressed, round 10)
// xt row byte offset = sp<<3 ( = src*1024 + r*128 )
// ---------------------------------------------------------------------------
__global__ __launch_bounds__(256) void agg1_kernel(const uint* __restrict__ off,
                                                   const uint* __restrict__ sp,
                                                   const float* __restrict__ idg,
                                                   const ushort* __restrict__ xt,
                                                   float* __restrict__ agg, int N) {
  int wid = (blockIdx.x * 256 + threadIdx.x) >> 6;
  if (wid >= N) return;
  int lane = threadIdx.x & 63;
  uint lane2 = (uint)lane * 2u;
  uint e0 = (uint)__builtin_amdgcn_readfirstlane((int)off[(size_t)wid * 8]);
  uint e1 = (uint)__builtin_amdgcn_readfirstlane((int)off[(size_t)wid * 8 + 8]);
  float idgl = (lane < 8) ? idg[(size_t)wid * 8 + lane] : 0.f;
  const char* xb = (const char*)xt;
  float acct = 0.f, accs = 0.f;
  uint cur = 0;
  for (uint b0 = e0; b0 < e1; b0 += 64) {
    uint vsp = sp[b0 + lane];                       // sp over-allocated by 64
    uint vpr = __shfl(vsp, ((int)lane - 1) & 63);
    unsigned long long bmv = __ballot(((vsp ^ vpr) & 0x70u) != 0u);
    uint blo = (uint)__builtin_amdgcn_readfirstlane((int)(uint)bmv);
    uint bhi = (uint)__builtin_amdgcn_readfirstlane((int)(uint)(bmv >> 32));
    uint f0  = (uint)__builtin_amdgcn_readlane((int)vsp, 0);
    if ((b0 == e0) || (((f0 ^ cur) & 0x70u) != 0u)) blo |= 1u; else blo &= ~1u;
    unsigned long long sbm = (((unsigned long long)bhi) << 32) | blo;
    int n = min(64, (int)(e1 - b0));
    int i = 0;
    for (; i + 8 <= n; i += 8) {
      uint p[8]; float v[8];
#pragma unroll
      for (int j = 0; j < 8; ++j)
        p[j] = (uint)__builtin_amdgcn_readlane((int)vsp, i + j);
#pragma unroll
      for (int j = 0; j < 8; ++j)
        v[j] = bf2f(*(const ushort*)(xb + (size_t)((p[j] << 3) + lane2)));
#pragma unroll
      for (int j = 0; j < 8; ++j) {
        if ((sbm >> j) & 1ull) {
          acct += accs * readlane_f(idgl, (int)((cur >> 4) & 7u));
          accs = 0.f; cur = p[j];
        }
        accs += v[j];
      }
      sbm >>= 8;
    }
    for (; i < n; ++i) {
      uint pp = (uint)__builtin_amdgcn_readlane((int)vsp, i);
      float vv = bf2f(*(const ushort*)(xb + (size_t)((pp << 3) + lane2)));
      if (sbm & 1ull) {
        acct += accs * readlane_f(idgl, (int)((cur >> 4) & 7u));
        accs = 0.f; cur = pp;
      }
      sbm >>= 1;
      accs += vv;
    }
  }
  acct += accs * readlane_f(idgl, (int)((cur >> 4) & 7u));
  agg[(size_t)wid * 64 + lane] = acct;
}

// ---------------------------------------------------------------------------
// y2[d][r][lane] = bf16( idg[d,r] * sum_{e in seg(d,r)} h[src_e][lane] )
// hb row byte offset = sp & ~127 ( = src*128 )
// ---------------------------------------------------------------------------
__global__ __launch_bounds__(256) void agg2_kernel(const uint* __restrict__ off,
                                                   const uint* __restrict__ sp,
                                                   const float* __restrict__ idg,
                                                   const ushort* __restrict__ hb,
                                                   ushort* __restrict__ y2, int N) {
  int wid = (blockIdx.x * 256 + threadIdx.x) >> 6;
  if (wid >= N) return;
  int lane = threadIdx.x & 63;
  uint lane2 = (uint)lane * 2u;
  uint e0 = (uint)__builtin_amdgcn_readfirstlane((int)off[(size_t)wid * 8]);
  uint e1 = (uint)__builtin_amdgcn_readfirstlane((int)off[(size_t)wid * 8 + 8]);
  float idgl = (lane < 8) ? idg[(size_t)wid * 8 + lane] : 0.f;
  const char* hbb = (const char*)hb;
  float accs = 0.f;
  uint cur = 0;
  bool live = false;
  uint written = 0;
  for (uint b0 = e0; b0 < e1; b0 += 64) {
    uint vsp = sp[b0 + lane];
    uint vpr = __shfl(vsp, ((int)lane - 1) & 63);
    unsigned long long bmv = __ballot(((vsp ^ vpr) & 0x70u) != 0u);
    uint blo = (uint)__builtin_amdgcn_readfirstlane((int)(uint)bmv);
    uint bhi = (uint)__builtin_amdgcn_readfirstlane((int)(uint)(bmv >> 32));
    uint f0  = (uint)__builtin_amdgcn_readlane((int)vsp, 0);
    if ((b0 == e0) || (((f0 ^ cur) & 0x70u) != 0u)) blo |= 1u; else blo &= ~1u;
    unsigned long long sbm = (((unsigned long long)bhi) << 32) | blo;
    int n = min(64, (int)(e1 - b0));
    int i = 0;
    for (; i + 8 <= n; i += 8) {
      uint p[8]; float v[8];
#pragma unroll
      for (int j = 0; j < 8; ++j)
        p[j] = (uint)__builtin_amdgcn_readlane((int)vsp, i + j);
#pragma unroll
      for (int j = 0; j < 8; ++j)
        v[j] = bf2f(*(const ushort*)(hbb + (size_t)((p[j] & ~127u) + lane2)));
#pragma unroll
      for (int j = 0; j < 8; ++j) {
        if ((sbm >> j) & 1ull) {
          if (live) {
            int r = (int)((cur >> 4) & 7u);
            y2[(size_t)wid * 512 + r * 64 + lane] = f2bf(accs * readlane_f(idgl, r));
            written |= 1u << r;
          }
          accs = 0.f; cur = p[j]; live = true;
        }
        accs += v[j];
      }
      sbm >>= 8;
    }
    for (; i < n; ++i) {
      uint pp = (uint)__builtin_amdgcn_readlane((int)vsp, i);
      float vv = bf2f(*(const ushort*)(hbb + (size_t)((pp & ~127u) + lane2)));
      if (sbm & 1ull) {
        if (live) {
          int r = (int)((cur >> 4) & 7u);
          y2[(size_t)wid * 512 + r * 64 + lane] = f2bf(accs * readlane_f(idgl, r));
          written |= 1u << r;
        }
        accs = 0.f; cur = pp; live = true;
      }
      sbm >>= 1;
      accs += vv;
    }
  }
  if (live) {
    int r = (int)((cur >> 4) & 7u);
    y2[(size_t)wid * 512 + r * 64 + lane] = f2bf(accs * readlane_f(idgl, r));
    written |= 1u << r;
  }
#pragma unroll
  for (int r = 0; r < 8; ++r)
    if (!((written >> r) & 1u))
      y2[(size_t)wid * 512 + r * 64 + lane] = 0;
}

// ---------------------------------------------------------------------------
// hb[m][n] = bf16( relu( agg[m][n] + (x root1)[m][n] + b1[n] ) )
// ---------------------------------------------------------------------------
__global__ __launch_bounds__(256) void reduce_h_kernel(const float* __restrict__ x,
                                                       const ushort* __restrict__ r1t,
                                                       const float* __restrict__ b1,
                                                       const float* __restrict__ agg,
                                                       ushort* __restrict__ hb, int M) {
  __shared__ __align__(16) ushort Axs[64][136];
  __shared__ __align__(16) ushort Bws[64][136];
  const int tid = threadIdx.x;
  const int w = tid >> 6, l = tid & 63;
  const int rows0 = blockIdx.x * 64;
#pragma unroll
  for (int i = 0; i < 8; ++i) {
    int g = tid + 256 * i;
    int row = g >> 5, c4 = (g & 31) * 4;
    int rr = rows0 + row; if (rr >= M) rr = M - 1;
    float4 v = *(const float4*)&x[(size_t)rr * 128 + c4];
    *(ushort4*)&Axs[row][c4] = make_ushort4(f2bf(v.x), f2bf(v.y), f2bf(v.z), f2bf(v.w));
    *(ushort4*)&Bws[row][c4] = *(const ushort4*)&r1t[(size_t)row * 128 + c4];
  }
  __syncthreads();
  const int mrow = w * 16 + (l & 15);
  const int koff = (l >> 4) * 8;
  const int m = rows0 + mrow;
  const int mc = (m < M) ? m : (M - 1);
  bfrag8 xf[4];
#pragma unroll
  for (int kc = 0; kc < 4; ++kc)
    xf[kc] = *(const bfrag8*)&Axs[mrow][kc * 32 + koff];
  facc4 acc[4] = {};
#pragma unroll
  for (int ct = 0; ct < 4; ++ct)
#pragma unroll
    for (int kc = 0; kc < 4; ++kc) {
      bfrag8 af = *(const bfrag8*)&Bws[ct * 16 + (l & 15)][kc * 32 + koff];
      acc[ct] = __builtin_amdgcn_mfma_f32_16x16x32_bf16(af, xf[kc], acc[ct], 0, 0, 0);
    }
#pragma unroll
  for (int ct = 0; ct < 4; ++ct) {
    int n0 = ct * 16 + (l >> 4) * 4;
    float4 s4 = *(const float4*)&agg[(size_t)mc * 64 + n0];
    float4 bb = *(const float4*)&b1[n0];
    float h0 = fmaxf(acc[ct][0] + s4.x + bb.x, 0.f);
    float h1 = fmaxf(acc[ct][1] + s4.y + bb.y, 0.f);
    float h2 = fmaxf(acc[ct][2] + s4.z + bb.z, 0.f);
    float h3 = fmaxf(acc[ct][3] + s4.w + bb.w, 0.f);
    if (m < M)
      *(ushort4*)&hb[(size_t)m * 64 + n0] =
          make_ushort4(f2bf(h0), f2bf(h1), f2bf(h2), f2bf(h3));
  }
}

// ---------------------------------------------------------------------------
// out[m][n] = sum_r y2[m][r][:] W2[r][:][n] + (h root2)[m][n] + b2[n]
// ---------------------------------------------------------------------------
__global__ __launch_bounds__(256) void gemm_out_kernel(const ushort* __restrict__ hb,
                                                       const ushort* __restrict__ y2,
                                                       const ushort* __restrict__ W2t,
                                                       const ushort* __restrict__ r2t,
                                                       const float* __restrict__ b2,
                                                       float* __restrict__ out, int M) {
  __shared__ __align__(16) ushort Bws[128][72];
  const int tid = threadIdx.x;
  const int w = tid >> 6, l = tid & 63;
  const int rows0 = blockIdx.x * 64;
  const int mrow = w * 16 + (l & 15);
  const int koff = (l >> 4) * 8;
  const int m = rows0 + mrow;
  const int mc = (m < M) ? m : (M - 1);
  facc4 oacc[8] = {};
  // ---- root2 part ----
#pragma unroll
  for (int i = 0; i < 8; ++i) {
    int g = tid + 256 * i;
    int row = g >> 4, c4 = (g & 15) * 4;
    *(ushort4*)&Bws[row][c4] = *(const ushort4*)&r2t[(size_t)row * 64 + c4];
  }
  __syncthreads();
  {
    bfrag8 h0 = *(const bfrag8*)&hb[(size_t)mc * 64 + koff];
    bfrag8 h1 = *(const bfrag8*)&hb[(size_t)mc * 64 + 32 + koff];
#pragma unroll
    for (int ct = 0; ct < 8; ++ct) {
      bfrag8 a0 = *(const bfrag8*)&Bws[ct * 16 + (l & 15)][koff];
      bfrag8 a1 = *(const bfrag8*)&Bws[ct * 16 + (l & 15)][32 + koff];
      oacc[ct] = __builtin_amdgcn_mfma_f32_16x16x32_bf16(a0, h0, oacc[ct], 0, 0, 0);
      oacc[ct] = __builtin_amdgcn_mfma_f32_16x16x32_bf16(a1, h1, oacc[ct], 0, 0, 0);
    }
  }
  // ---- relation parts (y2 already normalized) ----
  for (int r = 0; r < NREL; ++r) {
    __syncthreads();
#pragma unroll
    for (int i = 0; i < 8; ++i) {
      int g = tid + 256 * i;
      int row = g >> 4, c4 = (g & 15) * 4;
      *(ushort4*)&Bws[row][c4] = *(const ushort4*)&W2t[((size_t)r * 128 + row) * 64 + c4];
    }
    __syncthreads();
    bfrag8 y0 = *(const bfrag8*)&y2[(size_t)mc * 512 + r * 64 + koff];
    bfrag8 y1f = *(const bfrag8*)&y2[(size_t)mc * 512 + r * 64 + 32 + koff];
#pragma unroll
    for (int ct = 0; ct < 8; ++ct) {
      bfrag8 a0 = *(const bfrag8*)&Bws[ct * 16 + (l & 15)][koff];
      bfrag8 a1 = *(const bfrag8*)&Bws[ct * 16 + (l & 15)][32 + koff];
      oacc[ct] = __builtin_amdgcn_mfma_f32_16x16x32_bf16(a0, y0, oacc[ct], 0, 0, 0);
      oacc[ct] = __builtin_amdgcn_mfma_f32_16x16x32_bf16(a1, y1f, oacc[ct], 0, 0, 0);
    }
  }
  if (m < M) {
#pragma unroll
    for (int ct = 0; ct < 8; ++ct) {
      int n0 = ct * 16 + (l >> 4) * 4;
      float4 bb = *(const float4*)&b2[n0];
      float4 o = make_float4(oacc[ct][0] + bb.x, oacc[ct][1] + bb.y,
                             oacc[ct][2] + bb.z, oacc[ct][3] + bb.w);
      *(float4*)&out[(size_t)m * 128 + n0] = o;
    }
  }
}

// ---------------------------------------------------------------------------
extern "C" void kernel_launch(void* const* d_in, const int* in_sizes, int n_in,
                              void* d_out, int out_size, void* d_ws, size_t ws_size,
                              hipStream_t stream) {
  const float* x     = (const float*)d_in[0];
  const int*   ei    = (const int*)d_in[1];
  const int*   et    = (const int*)d_in[2];
  const float* W1    = (const float*)d_in[3];
  const float* root1 = (const float*)d_in[4];
  const float* b1    = (const float*)d_in[5];
  const float* W2    = (const float*)d_in[6];
  const float* root2 = (const float*)d_in[7];
  const float* b2    = (const float*)d_in[8];
  float* out = (float*)d_out;

  const int M = in_sizes[0] / 128;   // 100000
  const int E = in_sizes[2];         // 1600000
  const int NS = M * NREL;           // segments
  const int* srcp = ei;
  const int* dstp = ei + E;

  auto align = [](char*& p, size_t n) { char* q = p; p += (n + 255) & ~(size_t)255; return q; };
  char* p = (char*)d_ws;
  ushort* xt   = (ushort*)align(p, (size_t)M * 512 * 2);  // layer1 xt / layer2 y2 (alias)
  float*  agg  = (float*) align(p, (size_t)M * 64 * 4);
  ushort* hb   = (ushort*)align(p, (size_t)M * 64 * 2);
  uint*   hist = (uint*)  align(p, (size_t)NS * 4);
  uint*   rank = (uint*)  align(p, (size_t)E * 4);
  uint*   off  = (uint*)  align(p, (size_t)(NS + 1) * 4);
  float*  idg  = (float*) align(p, (size_t)NS * 4);
  uint*   sp   = (uint*)  align(p, (size_t)(E + 64) * 4);  // +64 over-read slack
  uint*   bsum = (uint*)  align(p, 4096);
  ushort* W1t  = (ushort*)align(p, (size_t)NREL * 64 * 128 * 2);
  ushort* r1t  = (ushort*)align(p, (size_t)64 * 128 * 2);
  ushort* W2t  = (ushort*)align(p, (size_t)NREL * 128 * 64 * 2);
  ushort* r2t  = (ushort*)align(p, (size_t)128 * 64 * 2);
  ushort* y2 = xt;

  cvt_all_kernel<<<(147456 + 255) / 256, 256, 0, stream>>>(W1, root1, W2, root2,
                                                           W1t, r1t, W2t, r2t);
  hipMemsetAsync(hist, 0, (size_t)NS * 4, stream);

  // ---- fused: hist(4/thread) || gemm_xt, 1:1 interleave ----
  const int E4B  = (int)(((long long)E + 4LL * 256 - 1) / (4LL * 256));
  const int MB64 = (M + 63) / 64;
  fused1_kernel<<<E4B + MB64, 256, 0, stream>>>(x, W1t, xt, dstp, et,
                                                hist, rank, M, E, E4B);

  // ---- scan -> place ----
  const int NB = (M + 255) / 256;
  scan1_kernel<<<NB, 256, 0, stream>>>(hist, bsum, M);
  scan2_kernel<<<1, 512, 0, stream>>>(bsum, NB);
  scan3_kernel<<<NB, 256, 0, stream>>>(hist, bsum, off, idg, M, E);
  const int E8B = (int)(((long long)E + 8LL * 256 - 1) / (8LL * 256));
  place_kernel<<<E8B, 256, 0, stream>>>(srcp, dstp, et, off, rank, sp, E);

  const int AGB = (M * 64 + 255) / 256;   // one wave per dst

  // ---- layer 1: sorted gather-aggregate -> root+relu ----
  agg1_kernel<<<AGB, 256, 0, stream>>>(off, sp, idg, xt, agg, M);
  reduce_h_kernel<<<MB64, 256, 0, stream>>>(x, r1t, b1, agg, hb, M);

  // ---- layer 2: sorted gather-aggregate (pre-normalized) -> fused GEMM ----
  agg2_kernel<<<AGB, 256, 0, stream>>>(off, sp, idg, hb, y2, M);
  gemm_out_kernel<<<MB64, 256, 0, stream>>>(hb, y2, W2t, r2t, b2, out, M);
}